// Round 3
// baseline (267.775 us; speedup 1.0000x reference)
//
#include <hip/hip_runtime.h>
#include <hip/hip_bf16.h>

// Shapes: B=512, BAG=32, H=1024, C=53.  EPS=1e-8, scale=sqrt(1024)=32.
// Out: bag_out (512*53=27136) f32, then cl_loss scalar -> 27137 floats.

typedef __bf16 bf16x8 __attribute__((ext_vector_type(8)));
typedef float  f32x4  __attribute__((ext_vector_type(4)));

__device__ inline float wsum(float v) {
    #pragma unroll
    for (int off = 32; off > 0; off >>= 1) v += __shfl_xor(v, off, 64);
    return v;
}

__device__ inline void gll16(const void* g, void* l) {
    __builtin_amdgcn_global_load_lds((const __attribute__((address_space(1))) void*)g,
                                     (__attribute__((address_space(3))) void*)l, 16, 0, 0);
}

// ---- k0: cls_w -> bf16, padded to 64 rows (rows 53..63 zero) ----
__global__ __launch_bounds__(256) void k0_cvt(const float* __restrict__ w, __bf16* __restrict__ wb)
{
    int i = blockIdx.x * 256 + threadIdx.x;            // 65536 total
    wb[i] = (i < 53 * 1024) ? (__bf16)w[i] : (__bf16)0.0f;
}

// ---- k12: fused per-b attention softmax + bag reps + per-(b,j) norms/pos_sim + bf16 repack
// One pass over sent (64 MB) instead of two.
__global__ __launch_bounds__(1024) void k12(
    const float* __restrict__ sent, const float* __restrict__ aug,
    const float* __restrict__ rel_table, const int* __restrict__ labels,
    __bf16* __restrict__ bagb, float* __restrict__ nb,
    __bf16* __restrict__ repb, float* __restrict__ nr, float* __restrict__ pos_sim)
{
    const int b = blockIdx.x, t = threadIdx.x;         // t = h in [0,1024)
    const int lane = t & 63, wave = t >> 6;            // 16 waves
    __shared__ float redS[32 * 16];                    // scores
    __shared__ float redR[32 * 16];                    // |rep|^2
    __shared__ float redA[32 * 16];                    // |aug|^2
    __shared__ float redD[32 * 16];                    // rep.aug
    __shared__ float alphas[32];
    __shared__ float r2[16];

    const float relh = rel_table[(size_t)labels[b] * 1024 + t];
    const float* s  = sent + (size_t)b * 32 * 1024;
    const float* ag = aug  + (size_t)b * 32 * 1024;
    float v[32];
    #pragma unroll
    for (int j = 0; j < 32; j++) v[j] = s[j * 1024 + t];

    #pragma unroll
    for (int j = 0; j < 32; j++) {
        float y = ag[j * 1024 + t];
        float p  = wsum(relh * v[j]);
        float sr = wsum(v[j] * v[j]);
        float sa = wsum(y * y);
        float sd = wsum(v[j] * y);
        if (lane == 0) {
            redS[j * 16 + wave] = p;  redR[j * 16 + wave] = sr;
            redA[j * 16 + wave] = sa; redD[j * 16 + wave] = sd;
        }
        repb[(size_t)(b * 32 + j) * 1024 + t] = (__bf16)v[j];
    }
    __syncthreads();

    if (wave == 0) {                                   // softmax over 32 scores
        float sj = 0.0f;
        if (lane < 32) {
            #pragma unroll
            for (int w = 0; w < 16; w++) sj += redS[lane * 16 + w];
            sj *= (1.0f / 32.0f);                      // /sqrt(H)
        }
        float m = sj;
        #pragma unroll
        for (int off = 16; off > 0; off >>= 1) m = fmaxf(m, __shfl_xor(m, off, 32));
        float e = __expf(sj - m);
        float sum = e;
        #pragma unroll
        for (int off = 16; off > 0; off >>= 1) sum += __shfl_xor(sum, off, 32);
        if (lane < 32) alphas[lane] = e / sum;
    } else if (wave == 1 && lane < 32) {               // norms finalize (concurrent)
        const int j = lane;
        float R = 0.f, A = 0.f, D = 0.f;
        #pragma unroll
        for (int w = 0; w < 16; w++) {
            R += redR[j * 16 + w]; A += redA[j * 16 + w]; D += redD[j * 16 + w];
        }
        float nrv = sqrtf(R), nav = sqrtf(A);
        nr[b * 32 + j] = nrv;
        pos_sim[b * 32 + j] = D / fmaxf(nrv * nav, 1e-8f);
    }
    __syncthreads();

    float bg = 0.0f;
    #pragma unroll
    for (int j = 0; j < 32; j++) bg += alphas[j] * v[j];
    bagb[(size_t)b * 1024 + t] = (__bf16)bg;

    float q = wsum(bg * bg);
    if (lane == 0) r2[wave] = q;
    __syncthreads();
    if (t == 0) {
        float s2 = 0.0f;
        #pragma unroll
        for (int w = 0; w < 16; w++) s2 += r2[w];
        nb[b] = sqrtf(s2);
    }
}

// ---- k3m: bag_out = bagb @ cwb^T + cls_b via MFMA, global_load_lds staging ----
__global__ __launch_bounds__(256) void k3m(
    const __bf16* __restrict__ bagb, const __bf16* __restrict__ cwb,
    const float* __restrict__ bias, float* __restrict__ out)
{
    __shared__ __align__(16) __bf16 Al[64 * 32];       // [row][k], no pad (gll dest)
    __shared__ __align__(16) __bf16 Bl[64 * 32];
    const int r0 = blockIdx.x * 64;                    // 8 blocks
    const int t = threadIdx.x, lane = t & 63, w = t >> 6;
    const int m = lane & 15, quad = lane >> 4;
    f32x4 acc[4] = {};

    const int i0 = t * 8;                              // tile bf16 idx, 2048/tile
    const int row0 = i0 >> 5, kk0 = i0 & 31;
    const __bf16* gA = bagb + (size_t)(r0 + row0) * 1024 + kk0;
    const __bf16* gB = cwb + (size_t)row0 * 1024 + kk0;

    for (int k0 = 0; k0 < 1024; k0 += 32) {
        __syncthreads();
        gll16(gA + k0, Al + i0);
        gll16(gB + k0, Bl + i0);
        __syncthreads();
        bf16x8 a = *(const bf16x8*)(&Al[(w * 16 + m) * 32 + quad * 8]);
        #pragma unroll
        for (int n = 0; n < 4; n++) {
            bf16x8 bf = *(const bf16x8*)(&Bl[(n * 16 + m) * 32 + quad * 8]);
            acc[n] = __builtin_amdgcn_mfma_f32_16x16x32_bf16(a, bf, acc[n], 0, 0, 0);
        }
    }
    #pragma unroll
    for (int n = 0; n < 4; n++) {
        const int c = n * 16 + m;
        if (c < 53) {
            #pragma unroll
            for (int i = 0; i < 4; i++) {
                const int r = r0 + w * 16 + quad * 4 + i;
                out[(size_t)r * 53 + c] = acc[n][i] + bias[c];
            }
        }
    }
}

// ---- k4: E(bf16) = exp(pair/T) via MFMA, 128x128 tile, gll staging, XCD swizzle ----
__global__ __launch_bounds__(256) void k4_gemm(
    const __bf16* __restrict__ repb, const __bf16* __restrict__ bagb,
    const float* __restrict__ nr, const float* __restrict__ nb,
    const float* __restrict__ temp, __bf16* __restrict__ E)
{
    __shared__ __align__(16) __bf16 Al[128 * 32];      // [row][k], no pad
    __shared__ __align__(16) __bf16 Bl[128 * 32];
    // swizzle: 4 cb-siblings of each rb land on the same XCD (bid % 8 == rb % 8)
    const int bid = blockIdx.x;
    const int xcd = bid & 7, slot = bid >> 3;
    const int cb = slot & 3, rb = (slot >> 2) * 8 + xcd;
    const int r0 = rb * 128, c0 = cb * 128;
    const int t = threadIdx.x, lane = t & 63, w = t >> 6;
    const int m = lane & 15, quad = lane >> 4;
    const int wr0 = (w & 1) * 64, wc0 = (w >> 1) * 64; // 2x2 wave grid

    f32x4 acc[4][4] = {};

    const int i0 = t * 8, i1 = 2048 + t * 8;
    const int row0 = i0 >> 5, kk0 = i0 & 31;
    const int row1 = i1 >> 5, kk1 = i1 & 31;
    const __bf16* gA0 = repb + (size_t)(r0 + row0) * 1024 + kk0;
    const __bf16* gA1 = repb + (size_t)(r0 + row1) * 1024 + kk1;
    const __bf16* gB0 = bagb + (size_t)(c0 + row0) * 1024 + kk0;
    const __bf16* gB1 = bagb + (size_t)(c0 + row1) * 1024 + kk1;

    for (int k0 = 0; k0 < 1024; k0 += 32) {
        __syncthreads();
        gll16(gA0 + k0, Al + i0);
        gll16(gA1 + k0, Al + i1);
        gll16(gB0 + k0, Bl + i0);
        gll16(gB1 + k0, Bl + i1);
        __syncthreads();
        bf16x8 a[4], bf[4];
        #pragma unroll
        for (int i = 0; i < 4; i++) a[i]  = *(const bf16x8*)(&Al[(wr0 + i * 16 + m) * 32 + quad * 8]);
        #pragma unroll
        for (int n = 0; n < 4; n++) bf[n] = *(const bf16x8*)(&Bl[(wc0 + n * 16 + m) * 32 + quad * 8]);
        #pragma unroll
        for (int i = 0; i < 4; i++)
            #pragma unroll
            for (int n = 0; n < 4; n++)
                acc[i][n] = __builtin_amdgcn_mfma_f32_16x16x32_bf16(a[i], bf[n], acc[i][n], 0, 0, 0);
    }

    const float invT = 1.0f / *temp;
    float nrv[16];
    #pragma unroll
    for (int i = 0; i < 4; i++)
        #pragma unroll
        for (int g = 0; g < 4; g++)
            nrv[i * 4 + g] = nr[r0 + wr0 + i * 16 + quad * 4 + g];
    #pragma unroll
    for (int n = 0; n < 4; n++) {
        const int c = c0 + wc0 + n * 16 + m;
        const float nbv = nb[c];
        #pragma unroll
        for (int i = 0; i < 4; i++) {
            #pragma unroll
            for (int g = 0; g < 4; g++) {
                const int r = r0 + wr0 + i * 16 + quad * 4 + g;
                float pair = acc[i][n][g] / fmaxf(nbv * nrv[i * 4 + g], 1e-8f);
                E[(size_t)r * 512 + c] = (__bf16)__expf(pair * invT);
            }
        }
    }
}

// ---- k5: neg + per-element loss; 256 blocks (j x ctile), 4 waves split b ----
__global__ __launch_bounds__(256) void k5_neg(
    const __bf16* __restrict__ E, const float* __restrict__ pos_sim,
    const float* __restrict__ temp, float* __restrict__ bsums)
{
    const int ct = blockIdx.x & 7, j = blockIdx.x >> 3;
    const int t = threadIdx.x, lane = t & 63, w = t >> 6;
    const int c = ct * 64 + lane;
    __shared__ float red[4][64];

    float s = 0.f;
    const __bf16* base = E + (size_t)j * 512 + c;
    #pragma unroll 8
    for (int b = w * 128; b < w * 128 + 128; b++)
        s += (float)base[(size_t)b * 16384];           // b*32*512
    red[w][lane] = s;
    __syncthreads();

    if (t < 64) {
        const int cc = ct * 64 + t;
        float S = red[0][t] + red[1][t] + red[2][t] + red[3][t];
        S -= (float)E[(size_t)((cc << 5) + j) * 512 + cc];  // exact diagonal cancellation
        const float invT = 1.0f / *temp;
        const float lp = pos_sim[(cc << 5) + j] * invT;
        float term = logf(__expf(lp) + S) - lp;
        term = wsum(term);
        if (t == 0) bsums[blockIdx.x] = term;
    }
}

__global__ __launch_bounds__(256) void k6_final(const float* __restrict__ bsums, float* __restrict__ loss)
{
    const int t = threadIdx.x;
    float v = bsums[t];
    v = wsum(v);
    __shared__ float r[4];
    if ((t & 63) == 0) r[t >> 6] = v;
    __syncthreads();
    if (t == 0) *loss = (r[0] + r[1] + r[2] + r[3]) * (1.0f / 16384.0f);
}

extern "C" void kernel_launch(void* const* d_in, const int* in_sizes, int n_in,
                              void* d_out, int out_size, void* d_ws, size_t ws_size,
                              hipStream_t stream)
{
    const float* sent = (const float*)d_in[0];
    const float* aug  = (const float*)d_in[1];
    const float* rel  = (const float*)d_in[2];
    const float* clsw = (const float*)d_in[3];
    const float* clsb = (const float*)d_in[4];
    const int*   lab  = (const int*)d_in[5];
    const float* temp = (const float*)d_in[6];
    float* out = (float*)d_out;

    char* ws = (char*)d_ws;
    __bf16* bagb  = (__bf16*)(ws);                           // 1 MB
    float*  nb    = (float*)(ws + (1u << 20));               // 2 KB
    float*  nr    = (float*)(ws + (1u << 20) + 65536);       // 64 KB
    float*  pos   = (float*)(ws + (1u << 20) + 2 * 65536);   // 64 KB
    __bf16* cwb   = (__bf16*)(ws + (1u << 20) + 3 * 65536);  // 128 KB
    float*  bsums = (float*)(ws + (2u << 20));               // 1 KB
    __bf16* repb  = (__bf16*)(ws + (4u << 20));              // 32 MB
    __bf16* E     = (__bf16*)(ws + (36u << 20));             // 16 MB

    k0_cvt  <<<256, 256, 0, stream>>>(clsw, cwb);
    k12     <<<512, 1024, 0, stream>>>(sent, aug, rel, lab, bagb, nb, repb, nr, pos);
    k3m     <<<8, 256, 0, stream>>>(bagb, cwb, clsb, out);
    k4_gemm <<<512, 256, 0, stream>>>(repb, bagb, nr, nb, temp, E);
    k5_neg  <<<256, 256, 0, stream>>>(E, pos, temp, bsums);
    k6_final<<<1, 256, 0, stream>>>(bsums, out + 27136);
}

// Round 4
// 220.378 us; speedup vs baseline: 1.2151x; 1.2151x over previous
//
#include <hip/hip_runtime.h>
#include <hip/hip_bf16.h>

// Shapes: B=512, BAG=32, H=1024, C=53.  EPS=1e-8, scale=sqrt(1024)=32.
// Out: bag_out (512*53=27136) f32, then cl_loss scalar -> 27137 floats.

typedef __bf16 bf16x8 __attribute__((ext_vector_type(8)));
typedef __bf16 bf16x4 __attribute__((ext_vector_type(4)));
typedef float  f32x4  __attribute__((ext_vector_type(4)));

__device__ inline float wsum(float v) {
    #pragma unroll
    for (int off = 32; off > 0; off >>= 1) v += __shfl_xor(v, off, 64);
    return v;
}

__device__ inline void gll16(const void* g, void* l) {
    __builtin_amdgcn_global_load_lds((const __attribute__((address_space(1))) void*)g,
                                     (__attribute__((address_space(3))) void*)l, 16, 0, 0);
}

// ---- k0: cls_w -> bf16 (padded to 64 rows), zero nbsq ----
__global__ __launch_bounds__(256) void k0_cvt(const float* __restrict__ w, __bf16* __restrict__ wb,
                                              float* __restrict__ nbsq)
{
    int i = blockIdx.x * 256 + threadIdx.x;            // 65536 total
    wb[i] = (i < 53 * 1024) ? (__bf16)w[i] : (__bf16)0.0f;
    if (i < 512) nbsq[i] = 0.0f;
}

// ---- k12: fused attention + bag + norms + pos_sim + bf16 repack; shuffle-light ----
// block = one b, 256 threads. thread t: j = t>>3, seg = t&7 (128 floats, strided f32x4).
__global__ __launch_bounds__(256) void k12(
    const float* __restrict__ sent, const float* __restrict__ aug,
    const float* __restrict__ rel_table, const int* __restrict__ labels,
    __bf16* __restrict__ bagb, float* __restrict__ nbsq,
    __bf16* __restrict__ repb, float* __restrict__ nr, float* __restrict__ pos_sim,
    float* __restrict__ scoreg, float* __restrict__ alphag)
{
    __shared__ __bf16 Vb[32 * 1024];                   // 64 KB (LDS full; scalars go via global)
    const int b = blockIdx.x, t = threadIdx.x;
    const int j = t >> 3, seg = t & 7;
    const int lane = t & 63;

    const size_t rbase = (size_t)(b * 32 + j) * 1024;
    const float* srow = sent + rbase;
    const float* arow = aug + rbase;
    const float* relp = rel_table + (size_t)labels[b] * 1024;

    float P = 0.f, R = 0.f, A = 0.f, D = 0.f;
    #pragma unroll 8
    for (int i = 0; i < 32; i++) {
        const int h = i * 32 + seg * 4;                // j-group covers 128 B contiguous
        f32x4 v  = *(const f32x4*)(srow + h);
        f32x4 a  = *(const f32x4*)(arow + h);
        f32x4 rl = *(const f32x4*)(relp + h);
        P += v.x * rl.x + v.y * rl.y + v.z * rl.z + v.w * rl.w;
        R += v.x * v.x + v.y * v.y + v.z * v.z + v.w * v.w;
        A += a.x * a.x + a.y * a.y + a.z * a.z + a.w * a.w;
        D += v.x * a.x + v.y * a.y + v.z * a.z + v.w * a.w;
        bf16x4 vb = { (__bf16)v.x, (__bf16)v.y, (__bf16)v.z, (__bf16)v.w };
        // 1-bit XOR swizzle on the 32-float i-block breaks the 8-way write conflict to 4-way
        *(bf16x4*)(&Vb[j * 1024 + (i ^ (j & 1)) * 32 + seg * 4]) = vb;
        *(bf16x4*)(repb + rbase + h) = vb;
    }
    // reduce P/R/A/D over the 8 seg-lanes (12 shfls total)
    #pragma unroll
    for (int off = 1; off <= 4; off <<= 1) {
        P += __shfl_xor(P, off, 64);
        R += __shfl_xor(R, off, 64);
        A += __shfl_xor(A, off, 64);
        D += __shfl_xor(D, off, 64);
    }
    if (seg == 0) {
        scoreg[b * 32 + j] = P * (1.0f / 32.0f);       // /sqrt(H)
        float nrv = sqrtf(R), nav = sqrtf(A);
        nr[b * 32 + j] = nrv;
        pos_sim[b * 32 + j] = D / fmaxf(nrv * nav, 1e-8f);
    }
    __threadfence_block();
    __syncthreads();

    if (t < 32) {                                      // softmax over the 32 scores
        float sj = scoreg[b * 32 + t];
        float m = sj;
        #pragma unroll
        for (int off = 16; off > 0; off >>= 1) m = fmaxf(m, __shfl_xor(m, off, 32));
        float e = __expf(sj - m);
        float sum = e;
        #pragma unroll
        for (int off = 16; off > 0; off >>= 1) sum += __shfl_xor(sum, off, 32);
        alphag[b * 32 + t] = e / sum;
    }
    __threadfence_block();
    __syncthreads();

    // bag pass: thread t owns h = t*4..t*4+3; read Vb transposed (4-way = b64 floor)
    f32x4 bag = {0.f, 0.f, 0.f, 0.f};
    #pragma unroll 8
    for (int jj = 0; jj < 32; jj++) {
        const float al = alphag[b * 32 + jj];          // uniform -> broadcast, L1-hot
        bf16x4 vb = *(const bf16x4*)(&Vb[jj * 1024 + ((t >> 3) ^ (jj & 1)) * 32 + (t & 7) * 4]);
        bag.x += al * (float)vb.x;
        bag.y += al * (float)vb.y;
        bag.z += al * (float)vb.z;
        bag.w += al * (float)vb.w;
    }
    bf16x4 bb = { (__bf16)bag.x, (__bf16)bag.y, (__bf16)bag.z, (__bf16)bag.w };
    *(bf16x4*)(bagb + (size_t)b * 1024 + t * 4) = bb;

    float q = bag.x * bag.x + bag.y * bag.y + bag.z * bag.z + bag.w * bag.w;
    q = wsum(q);
    if (lane == 0) atomicAdd(&nbsq[b], q);
}

// ---- k3m: bag_out = bagb @ cwb^T + cls_b via MFMA, global_load_lds staging ----
__global__ __launch_bounds__(256) void k3m(
    const __bf16* __restrict__ bagb, const __bf16* __restrict__ cwb,
    const float* __restrict__ bias, float* __restrict__ out)
{
    __shared__ __align__(16) __bf16 Al[64 * 32];       // [row][k], no pad (gll dest)
    __shared__ __align__(16) __bf16 Bl[64 * 32];
    const int r0 = blockIdx.x * 64;                    // 8 blocks
    const int t = threadIdx.x, lane = t & 63, w = t >> 6;
    const int m = lane & 15, quad = lane >> 4;
    f32x4 acc[4] = {};

    const int i0 = t * 8;
    const int row0 = i0 >> 5, kk0 = i0 & 31;
    const __bf16* gA = bagb + (size_t)(r0 + row0) * 1024 + kk0;
    const __bf16* gB = cwb + (size_t)row0 * 1024 + kk0;

    for (int k0 = 0; k0 < 1024; k0 += 32) {
        __syncthreads();
        gll16(gA + k0, Al + i0);
        gll16(gB + k0, Bl + i0);
        __syncthreads();
        bf16x8 a = *(const bf16x8*)(&Al[(w * 16 + m) * 32 + quad * 8]);
        #pragma unroll
        for (int n = 0; n < 4; n++) {
            bf16x8 bf = *(const bf16x8*)(&Bl[(n * 16 + m) * 32 + quad * 8]);
            acc[n] = __builtin_amdgcn_mfma_f32_16x16x32_bf16(a, bf, acc[n], 0, 0, 0);
        }
    }
    #pragma unroll
    for (int n = 0; n < 4; n++) {
        const int c = n * 16 + m;
        if (c < 53) {
            #pragma unroll
            for (int i = 0; i < 4; i++) {
                const int r = r0 + w * 16 + quad * 4 + i;
                out[(size_t)r * 53 + c] = acc[n][i] + bias[c];
            }
        }
    }
}

// ---- k4: E(bf16) = exp(pair/T) via MFMA, 128x128 tile, gll staging, XCD swizzle ----
__global__ __launch_bounds__(256) void k4_gemm(
    const __bf16* __restrict__ repb, const __bf16* __restrict__ bagb,
    const float* __restrict__ nr, const float* __restrict__ nbsq,
    const float* __restrict__ temp, __bf16* __restrict__ E)
{
    __shared__ __align__(16) __bf16 Al[128 * 32];      // [row][k], no pad
    __shared__ __align__(16) __bf16 Bl[128 * 32];
    const int bid = blockIdx.x;
    const int xcd = bid & 7, slot = bid >> 3;
    const int cb = slot & 3, rb = (slot >> 2) * 8 + xcd;
    const int r0 = rb * 128, c0 = cb * 128;
    const int t = threadIdx.x, lane = t & 63, w = t >> 6;
    const int m = lane & 15, quad = lane >> 4;
    const int wr0 = (w & 1) * 64, wc0 = (w >> 1) * 64;

    f32x4 acc[4][4] = {};

    const int i0 = t * 8, i1 = 2048 + t * 8;
    const int row0 = i0 >> 5, kk0 = i0 & 31;
    const int row1 = i1 >> 5, kk1 = i1 & 31;
    const __bf16* gA0 = repb + (size_t)(r0 + row0) * 1024 + kk0;
    const __bf16* gA1 = repb + (size_t)(r0 + row1) * 1024 + kk1;
    const __bf16* gB0 = bagb + (size_t)(c0 + row0) * 1024 + kk0;
    const __bf16* gB1 = bagb + (size_t)(c0 + row1) * 1024 + kk1;

    for (int k0 = 0; k0 < 1024; k0 += 32) {
        __syncthreads();
        gll16(gA0 + k0, Al + i0);
        gll16(gA1 + k0, Al + i1);
        gll16(gB0 + k0, Bl + i0);
        gll16(gB1 + k0, Bl + i1);
        __syncthreads();
        bf16x8 a[4], bf[4];
        #pragma unroll
        for (int i = 0; i < 4; i++) a[i]  = *(const bf16x8*)(&Al[(wr0 + i * 16 + m) * 32 + quad * 8]);
        #pragma unroll
        for (int n = 0; n < 4; n++) bf[n] = *(const bf16x8*)(&Bl[(wc0 + n * 16 + m) * 32 + quad * 8]);
        #pragma unroll
        for (int i = 0; i < 4; i++)
            #pragma unroll
            for (int n = 0; n < 4; n++)
                acc[i][n] = __builtin_amdgcn_mfma_f32_16x16x32_bf16(a[i], bf[n], acc[i][n], 0, 0, 0);
    }

    const float invT = 1.0f / *temp;
    float nrv[16];
    #pragma unroll
    for (int i = 0; i < 4; i++)
        #pragma unroll
        for (int g = 0; g < 4; g++)
            nrv[i * 4 + g] = nr[r0 + wr0 + i * 16 + quad * 4 + g];
    #pragma unroll
    for (int n = 0; n < 4; n++) {
        const int c = c0 + wc0 + n * 16 + m;
        const float nbv = sqrtf(nbsq[c]);
        #pragma unroll
        for (int i = 0; i < 4; i++) {
            #pragma unroll
            for (int g = 0; g < 4; g++) {
                const int r = r0 + wr0 + i * 16 + quad * 4 + g;
                float pair = acc[i][n][g] / fmaxf(nbv * nrv[i * 4 + g], 1e-8f);
                E[(size_t)r * 512 + c] = (__bf16)__expf(pair * invT);
            }
        }
    }
}

// ---- k5: neg + per-element loss; 256 blocks (j x ctile); 16B vector loads ----
__global__ __launch_bounds__(256) void k5_neg(
    const __bf16* __restrict__ E, const float* __restrict__ pos_sim,
    const float* __restrict__ temp, float* __restrict__ bsums)
{
    const int ct = blockIdx.x & 7, j = blockIdx.x >> 3;
    const int t = threadIdx.x, lane = t & 63, w = t >> 6;
    const int c8 = t & 7;                              // 8-col subchunk
    const int bsub = t >> 3;                           // 0..31
    const size_t cbase = (size_t)ct * 64 + c8 * 8;

    float acc[8] = {};
    #pragma unroll 4
    for (int it = 0; it < 16; it++) {
        const int b = it * 32 + bsub;
        bf16x8 v = *(const bf16x8*)(E + (size_t)(b * 32 + j) * 512 + cbase);
        #pragma unroll
        for (int k = 0; k < 8; k++) acc[k] += (float)v[k];
    }
    #pragma unroll
    for (int k = 0; k < 8; k++) {
        acc[k] += __shfl_xor(acc[k], 8, 64);
        acc[k] += __shfl_xor(acc[k], 16, 64);
        acc[k] += __shfl_xor(acc[k], 32, 64);
    }
    __shared__ float red[4][64];
    if (lane < 8) {
        #pragma unroll
        for (int k = 0; k < 8; k++) red[w][lane * 8 + k] = acc[k];
    }
    __syncthreads();

    if (t < 64) {
        const int cc = ct * 64 + t;
        float S = red[0][t] + red[1][t] + red[2][t] + red[3][t];
        S -= (float)E[(size_t)((cc << 5) + j) * 512 + cc];  // exact diagonal cancellation
        const float invT = 1.0f / *temp;
        const float lp = pos_sim[(cc << 5) + j] * invT;
        float term = logf(__expf(lp) + S) - lp;
        term = wsum(term);
        if (t == 0) bsums[blockIdx.x] = term;
    }
}

__global__ __launch_bounds__(256) void k6_final(const float* __restrict__ bsums, float* __restrict__ loss)
{
    const int t = threadIdx.x;
    float v = bsums[t];
    v = wsum(v);
    __shared__ float r[4];
    if ((t & 63) == 0) r[t >> 6] = v;
    __syncthreads();
    if (t == 0) *loss = (r[0] + r[1] + r[2] + r[3]) * (1.0f / 16384.0f);
}

extern "C" void kernel_launch(void* const* d_in, const int* in_sizes, int n_in,
                              void* d_out, int out_size, void* d_ws, size_t ws_size,
                              hipStream_t stream)
{
    const float* sent = (const float*)d_in[0];
    const float* aug  = (const float*)d_in[1];
    const float* rel  = (const float*)d_in[2];
    const float* clsw = (const float*)d_in[3];
    const float* clsb = (const float*)d_in[4];
    const int*   lab  = (const int*)d_in[5];
    const float* temp = (const float*)d_in[6];
    float* out = (float*)d_out;

    char* ws = (char*)d_ws;
    __bf16* bagb   = (__bf16*)(ws);                            // 1 MB
    float*  nbsq   = (float*)(ws + (1u << 20));                // 2 KB
    float*  nr     = (float*)(ws + (1u << 20) + 64 * 1024);    // 64 KB
    float*  pos    = (float*)(ws + (1u << 20) + 128 * 1024);   // 64 KB
    __bf16* cwb    = (__bf16*)(ws + (1u << 20) + 192 * 1024);  // 128 KB
    float*  scoreg = (float*)(ws + (1u << 20) + 320 * 1024);   // 64 KB
    float*  alphag = (float*)(ws + (1u << 20) + 384 * 1024);   // 64 KB
    float*  bsums  = (float*)(ws + (2u << 20));                // 1 KB
    __bf16* repb   = (__bf16*)(ws + (4u << 20));               // 32 MB
    __bf16* E      = (__bf16*)(ws + (36u << 20));              // 16 MB

    k0_cvt  <<<256, 256, 0, stream>>>(clsw, cwb, nbsq);
    k12     <<<512, 256, 0, stream>>>(sent, aug, rel, lab, bagb, nbsq, repb, nr, pos, scoreg, alphag);
    k3m     <<<8, 256, 0, stream>>>(bagb, cwb, clsb, out);
    k4_gemm <<<512, 256, 0, stream>>>(repb, bagb, nr, nbsq, temp, E);
    k5_neg  <<<256, 256, 0, stream>>>(E, pos, temp, bsums);
    k6_final<<<1, 256, 0, stream>>>(bsums, out + 27136);
}

// Round 5
// 215.278 us; speedup vs baseline: 1.2439x; 1.0237x over previous
//
#include <hip/hip_runtime.h>
#include <hip/hip_bf16.h>

// Shapes: B=512, BAG=32, H=1024, C=53.  EPS=1e-8, scale=sqrt(1024)=32.
// Out: bag_out (512*53=27136) f32, then cl_loss scalar -> 27137 floats.

typedef __bf16 bf16x8 __attribute__((ext_vector_type(8)));
typedef __bf16 bf16x4 __attribute__((ext_vector_type(4)));
typedef __bf16 bf16x2 __attribute__((ext_vector_type(2)));
typedef float  f32x4  __attribute__((ext_vector_type(4)));

__device__ inline float wsum(float v) {
    #pragma unroll
    for (int off = 32; off > 0; off >>= 1) v += __shfl_xor(v, off, 64);
    return v;
}

__device__ inline void gll16(const void* g, void* l) {
    __builtin_amdgcn_global_load_lds((const __attribute__((address_space(1))) void*)g,
                                     (__attribute__((address_space(3))) void*)l, 16, 0, 0);
}

// ---- k0: cls_w -> bf16 (padded to 64 rows), zero nbsq ----
__global__ __launch_bounds__(256) void k0_cvt(const float* __restrict__ w, __bf16* __restrict__ wb,
                                              float* __restrict__ nbsq)
{
    int i = blockIdx.x * 256 + threadIdx.x;            // 65536 total
    wb[i] = (i < 53 * 1024) ? (__bf16)w[i] : (__bf16)0.0f;
    if (i < 512) nbsq[i] = 0.0f;
}

// ---- k12: fused attention + bag + norms + pos_sim + bf16 repack; 512 thr, 16 waves/CU ----
__global__ __launch_bounds__(512, 4) void k12(
    const float* __restrict__ sent, const float* __restrict__ aug,
    const float* __restrict__ rel_table, const int* __restrict__ labels,
    __bf16* __restrict__ bagb, float* __restrict__ nbsq,
    __bf16* __restrict__ repb, float* __restrict__ nr, float* __restrict__ pos_sim)
{
    __shared__ __bf16 Vb[32 * 1024];                   // 64 KB
    __shared__ float scoreS[32];
    __shared__ float alphaS[32];
    const int b = blockIdx.x, t = threadIdx.x;
    const int j = t >> 4, seg = t & 15;                // 16 lanes per row j
    const int lane = t & 63;

    const size_t rbase = (size_t)(b * 32 + j) * 1024;
    const float* srow = sent + rbase;
    const float* arow = aug + rbase;
    const float* relp = rel_table + (size_t)labels[b] * 1024;

    float P = 0.f, R = 0.f, A = 0.f, D = 0.f;
    #pragma unroll 4
    for (int i = 0; i < 16; i++) {
        const int h = i * 64 + seg * 4;
        f32x4 v  = *(const f32x4*)(srow + h);
        f32x4 a  = *(const f32x4*)(arow + h);
        f32x4 rl = *(const f32x4*)(relp + h);
        P += v.x * rl.x + v.y * rl.y + v.z * rl.z + v.w * rl.w;
        R += v.x * v.x + v.y * v.y + v.z * v.z + v.w * v.w;
        A += a.x * a.x + a.y * a.y + a.z * a.z + a.w * a.w;
        D += v.x * a.x + v.y * a.y + v.z * a.z + v.w * a.w;
        bf16x4 vb = { (__bf16)v.x, (__bf16)v.y, (__bf16)v.z, (__bf16)v.w };
        const int g = i * 16 + seg;                    // XOR-swizzle low4 vs j
        *(bf16x4*)(&Vb[j * 1024 + (g ^ (j & 15)) * 4]) = vb;
        *(bf16x4*)(repb + rbase + h) = vb;
    }
    #pragma unroll
    for (int off = 1; off <= 8; off <<= 1) {           // reduce over 16 seg-lanes
        P += __shfl_xor(P, off, 64);
        R += __shfl_xor(R, off, 64);
        A += __shfl_xor(A, off, 64);
        D += __shfl_xor(D, off, 64);
    }
    if (seg == 0) {
        scoreS[j] = P * (1.0f / 32.0f);                // /sqrt(H)
        float nrv = sqrtf(R), nav = sqrtf(A);
        nr[b * 32 + j] = nrv;
        pos_sim[b * 32 + j] = D / fmaxf(nrv * nav, 1e-8f);
    }
    __syncthreads();

    if (t < 32) {                                      // softmax over 32 scores
        float sj = scoreS[t];
        float m = sj;
        #pragma unroll
        for (int off = 16; off > 0; off >>= 1) m = fmaxf(m, __shfl_xor(m, off, 32));
        float e = __expf(sj - m);
        float sum = e;
        #pragma unroll
        for (int off = 16; off > 0; off >>= 1) sum += __shfl_xor(sum, off, 32);
        alphaS[t] = e / sum;
    }
    __syncthreads();

    // bag pass: thread t owns h = t*2, t*2+1; b32 LDS reads (floor-level banking)
    float ax = 0.f, ay = 0.f;
    const int g2 = t >> 1, sub = t & 1;
    #pragma unroll 8
    for (int jj = 0; jj < 32; jj++) {
        const float al = alphaS[jj];                   // broadcast
        bf16x2 v2 = *(const bf16x2*)(&Vb[jj * 1024 + (g2 ^ (jj & 15)) * 4 + sub * 2]);
        ax += al * (float)v2.x;
        ay += al * (float)v2.y;
    }
    bf16x2 bb = { (__bf16)ax, (__bf16)ay };
    *(bf16x2*)(bagb + (size_t)b * 1024 + t * 2) = bb;

    float q = ax * ax + ay * ay;
    q = wsum(q);
    if (lane == 0) atomicAdd(&nbsq[b], q);
}

// ---- k3m: bag_out = bagb @ cwb^T + cls_b via MFMA, K-chunk 64, gll staging ----
__global__ __launch_bounds__(256) void k3m(
    const __bf16* __restrict__ bagb, const __bf16* __restrict__ cwb,
    const float* __restrict__ bias, float* __restrict__ out)
{
    __shared__ __align__(16) __bf16 Al[2 * 2048];      // two 64x32 sub-tiles
    __shared__ __align__(16) __bf16 Bl[2 * 2048];
    const int r0 = blockIdx.x * 64;                    // 8 blocks
    const int t = threadIdx.x, lane = t & 63, w = t >> 6;
    const int m = lane & 15, quad = lane >> 4;
    f32x4 acc[4] = {};

    const int i0 = t * 8;
    const int row0 = i0 >> 5, kk0 = i0 & 31;
    const __bf16* gA = bagb + (size_t)(r0 + row0) * 1024 + kk0;
    const __bf16* gB = cwb + (size_t)row0 * 1024 + kk0;

    for (int k0 = 0; k0 < 1024; k0 += 64) {
        __syncthreads();
        gll16(gA + k0,      Al + i0);
        gll16(gA + k0 + 32, Al + 2048 + i0);
        gll16(gB + k0,      Bl + i0);
        gll16(gB + k0 + 32, Bl + 2048 + i0);
        __syncthreads();
        #pragma unroll
        for (int ks = 0; ks < 2; ks++) {
            bf16x8 a = *(const bf16x8*)(&Al[ks * 2048 + (w * 16 + m) * 32 + quad * 8]);
            #pragma unroll
            for (int n = 0; n < 4; n++) {
                bf16x8 bf = *(const bf16x8*)(&Bl[ks * 2048 + (n * 16 + m) * 32 + quad * 8]);
                acc[n] = __builtin_amdgcn_mfma_f32_16x16x32_bf16(a, bf, acc[n], 0, 0, 0);
            }
        }
    }
    #pragma unroll
    for (int n = 0; n < 4; n++) {
        const int c = n * 16 + m;
        if (c < 53) {
            #pragma unroll
            for (int i = 0; i < 4; i++) {
                const int r = r0 + w * 16 + quad * 4 + i;
                out[(size_t)r * 53 + c] = acc[n][i] + bias[c];
            }
        }
    }
}

// ---- k4: MFMA 128x128 tile; fused exp + per-tile b-reduction -> partial[rb][32][512], diag ----
__global__ __launch_bounds__(256) void k4_gemm(
    const __bf16* __restrict__ repb, const __bf16* __restrict__ bagb,
    const float* __restrict__ nr, const float* __restrict__ nbsq,
    const float* __restrict__ temp, float* __restrict__ partial, float* __restrict__ diag)
{
    __shared__ __align__(16) __bf16 Al[128 * 32];      // [row][k], no pad
    __shared__ __align__(16) __bf16 Bl[128 * 32];
    __shared__ float negp[2][32][128];                 // 32 KB, unique-writer
    const int bid = blockIdx.x;
    const int xcd = bid & 7, slot = bid >> 3;
    const int cb = slot & 3, rb = (slot >> 2) * 8 + xcd;
    const int r0 = rb * 128, c0 = cb * 128;
    const int t = threadIdx.x, lane = t & 63, w = t >> 6;
    const int m = lane & 15, quad = lane >> 4;
    const int wr0 = (w & 1) * 64, wc0 = (w >> 1) * 64;
    const int half = w & 1;

    // zero negp (covered by first loop-iteration's barrier)
    #pragma unroll
    for (int z = 0; z < 32; z++) ((float*)negp)[z * 256 + t] = 0.f;

    f32x4 acc[4][4] = {};

    const int i0 = t * 8, i1 = 2048 + t * 8;
    const int row0 = i0 >> 5, kk0 = i0 & 31;
    const int row1 = i1 >> 5, kk1 = i1 & 31;
    const __bf16* gA0 = repb + (size_t)(r0 + row0) * 1024 + kk0;
    const __bf16* gA1 = repb + (size_t)(r0 + row1) * 1024 + kk1;
    const __bf16* gB0 = bagb + (size_t)(c0 + row0) * 1024 + kk0;
    const __bf16* gB1 = bagb + (size_t)(c0 + row1) * 1024 + kk1;

    for (int k0 = 0; k0 < 1024; k0 += 32) {
        __syncthreads();
        gll16(gA0 + k0, Al + i0);
        gll16(gA1 + k0, Al + i1);
        gll16(gB0 + k0, Bl + i0);
        gll16(gB1 + k0, Bl + i1);
        __syncthreads();
        bf16x8 a[4], bf[4];
        #pragma unroll
        for (int i = 0; i < 4; i++) a[i]  = *(const bf16x8*)(&Al[(wr0 + i * 16 + m) * 32 + quad * 8]);
        #pragma unroll
        for (int n = 0; n < 4; n++) bf[n] = *(const bf16x8*)(&Bl[(wc0 + n * 16 + m) * 32 + quad * 8]);
        #pragma unroll
        for (int i = 0; i < 4; i++)
            #pragma unroll
            for (int n = 0; n < 4; n++)
                acc[i][n] = __builtin_amdgcn_mfma_f32_16x16x32_bf16(a[i], bf[n], acc[i][n], 0, 0, 0);
    }

    const float invT = 1.0f / *temp;
    float nrv[16];
    #pragma unroll
    for (int i = 0; i < 4; i++)
        #pragma unroll
        for (int g = 0; g < 4; g++)
            nrv[i * 4 + g] = nr[r0 + wr0 + i * 16 + quad * 4 + g];

    #pragma unroll
    for (int n = 0; n < 4; n++) {
        const int c_local = wc0 + n * 16 + m;
        const int cg = c0 + c_local;
        const float nbv = sqrtf(nbsq[cg]);
        #pragma unroll
        for (int i = 0; i < 2; i++) {                  // parity pairs (i, i+2)
            #pragma unroll
            for (int g = 0; g < 4; g++) {
                const int jj = i * 16 + quad * 4 + g;
                const int rg0 = r0 + wr0 + i * 16 + quad * 4 + g;
                const int rg2 = rg0 + 32;
                float e0 = __expf(acc[i][n][g]     / fmaxf(nbv * nrv[i * 4 + g],       1e-8f) * invT);
                float e2 = __expf(acc[i + 2][n][g] / fmaxf(nbv * nrv[(i + 2) * 4 + g], 1e-8f) * invT);
                negp[half][jj][c_local] = e0 + e2;
                if ((rg0 >> 5) == cg) diag[(size_t)cg * 32 + jj] = e0;
                if ((rg2 >> 5) == cg) diag[(size_t)cg * 32 + jj] = e2;
            }
        }
    }
    __syncthreads();

    float* pout = partial + (size_t)rb * 32 * 512 + c0;
    #pragma unroll
    for (int v = 0; v < 4; v++) {
        const int idx = v * 1024 + t * 4;              // 0..4095
        const int jj = idx >> 7, cl = idx & 127;
        f32x4 a = *(const f32x4*)(&negp[0][jj][cl]);
        f32x4 bq = *(const f32x4*)(&negp[1][jj][cl]);
        f32x4 s = a + bq;
        *(f32x4*)(pout + (size_t)jj * 512 + cl) = s;
    }
}

// ---- k5: reduce partial over rb (128) + loss terms; 256 blocks ----
__global__ __launch_bounds__(256) void k5_neg(
    const float* __restrict__ partial, const float* __restrict__ diag,
    const float* __restrict__ pos_sim, const float* __restrict__ temp,
    float* __restrict__ bsums)
{
    const int ct = blockIdx.x & 7, j = blockIdx.x >> 3;
    const int t = threadIdx.x, lane = t & 63, w = t >> 6;
    const int bsub = t >> 4;                           // 0..15 (rb-group of 8)
    const int cidx = t & 15;                           // x4 cols
    f32x4 acc = {};
    #pragma unroll 4
    for (int r = 0; r < 8; r++) {
        const int rb = bsub * 8 + r;
        f32x4 v = *(const f32x4*)(partial + ((size_t)rb * 32 + j) * 512 + ct * 64 + cidx * 4);
        acc += v;
    }
    #pragma unroll
    for (int k = 0; k < 4; k++) {
        acc[k] += __shfl_xor(acc[k], 16, 64);
        acc[k] += __shfl_xor(acc[k], 32, 64);
    }
    __shared__ float red[4][64];
    if (lane < 16) {
        #pragma unroll
        for (int k = 0; k < 4; k++) red[w][lane * 4 + k] = acc[k];
    }
    __syncthreads();

    if (t < 64) {
        const int c = ct * 64 + t;
        float S = red[0][t] + red[1][t] + red[2][t] + red[3][t];
        S -= diag[(size_t)c * 32 + j];                 // near-exact cancellation (f32)
        const float invT = 1.0f / *temp;
        const float lp = pos_sim[(c << 5) + j] * invT;
        float term = logf(__expf(lp) + S) - lp;
        term = wsum(term);
        if (t == 0) bsums[blockIdx.x] = term;
    }
}

__global__ __launch_bounds__(256) void k6_final(const float* __restrict__ bsums, float* __restrict__ loss)
{
    const int t = threadIdx.x;
    float v = bsums[t];
    v = wsum(v);
    __shared__ float r[4];
    if ((t & 63) == 0) r[t >> 6] = v;
    __syncthreads();
    if (t == 0) *loss = (r[0] + r[1] + r[2] + r[3]) * (1.0f / 16384.0f);
}

extern "C" void kernel_launch(void* const* d_in, const int* in_sizes, int n_in,
                              void* d_out, int out_size, void* d_ws, size_t ws_size,
                              hipStream_t stream)
{
    const float* sent = (const float*)d_in[0];
    const float* aug  = (const float*)d_in[1];
    const float* rel  = (const float*)d_in[2];
    const float* clsw = (const float*)d_in[3];
    const float* clsb = (const float*)d_in[4];
    const int*   lab  = (const int*)d_in[5];
    const float* temp = (const float*)d_in[6];
    float* out = (float*)d_out;

    char* ws = (char*)d_ws;
    __bf16* bagb    = (__bf16*)(ws);                           // 1 MB
    float*  nbsq    = (float*)(ws + (1u << 20));               // 2 KB
    float*  nr      = (float*)(ws + (1u << 20) + 64 * 1024);   // 64 KB
    float*  pos     = (float*)(ws + (1u << 20) + 128 * 1024);  // 64 KB
    __bf16* cwb     = (__bf16*)(ws + (1u << 20) + 192 * 1024); // 128 KB
    float*  bsums   = (float*)(ws + (2u << 20));               // 1 KB
    float*  diag    = (float*)(ws + (2u << 20) + 64 * 1024);   // 64 KB
    __bf16* repb    = (__bf16*)(ws + (4u << 20));              // 32 MB
    float*  partial = (float*)(ws + (36u << 20));              // 8 MB (128*32*512 f32)

    k0_cvt  <<<256, 256, 0, stream>>>(clsw, cwb, nbsq);
    k12     <<<512, 512, 0, stream>>>(sent, aug, rel, lab, bagb, nbsq, repb, nr, pos);
    k3m     <<<8, 256, 0, stream>>>(bagb, cwb, clsb, out);
    k4_gemm <<<512, 256, 0, stream>>>(repb, bagb, nr, nbsq, temp, partial, diag);
    k5_neg  <<<256, 256, 0, stream>>>(partial, diag, pos, temp, bsums);
    k6_final<<<1, 256, 0, stream>>>(bsums, out + 27136);
}

// Round 6
// 214.068 us; speedup vs baseline: 1.2509x; 1.0057x over previous
//
#include <hip/hip_runtime.h>
#include <hip/hip_bf16.h>

// Shapes: B=512, BAG=32, H=1024, C=53.  EPS=1e-8, scale=sqrt(1024)=32.
// Out: bag_out (512*53=27136) f32, then cl_loss scalar -> 27137 floats.

typedef __bf16 bf16x8 __attribute__((ext_vector_type(8)));
typedef __bf16 bf16x4 __attribute__((ext_vector_type(4)));
typedef float  f32x4  __attribute__((ext_vector_type(4)));

__device__ inline float wsum(float v) {
    #pragma unroll
    for (int off = 32; off > 0; off >>= 1) v += __shfl_xor(v, off, 64);
    return v;
}

__device__ inline void gll16(const void* g, void* l) {
    __builtin_amdgcn_global_load_lds((const __attribute__((address_space(1))) void*)g,
                                     (__attribute__((address_space(3))) void*)l, 16, 0, 0);
}

// ---- k0: cls_w -> bf16 (padded to 64 rows), zero nbsq ----
__global__ __launch_bounds__(256) void k0_cvt(const float* __restrict__ w, __bf16* __restrict__ wb,
                                              float* __restrict__ nbsq)
{
    int i = blockIdx.x * 256 + threadIdx.x;            // 65536 total
    wb[i] = (i < 53 * 1024) ? (__bf16)w[i] : (__bf16)0.0f;
    if (i < 512) nbsq[i] = 0.0f;
}

// ---- ka: pure streaming — repack + norms + pos_sim + scores. wave-per-row, no LDS/barriers ----
__global__ __launch_bounds__(256) void ka(
    const float* __restrict__ sent, const float* __restrict__ aug,
    const float* __restrict__ rel_table, const int* __restrict__ labels,
    __bf16* __restrict__ repb, float* __restrict__ nr, float* __restrict__ pos_sim,
    float* __restrict__ scoreg)
{
    const int w = threadIdx.x >> 6, lane = threadIdx.x & 63;
    const int row = blockIdx.x * 4 + w;                // 0..16383 (wave-uniform)
    const int b = row >> 5;
    const size_t rbase = (size_t)row * 1024;
    const float* srow = sent + rbase;
    const float* arow = aug + rbase;
    const float* relp = rel_table + (size_t)labels[b] * 1024;

    float P = 0.f, R = 0.f, A = 0.f, D = 0.f;
    #pragma unroll
    for (int i = 0; i < 4; i++) {
        const int h = i * 256 + lane * 4;
        f32x4 v  = *(const f32x4*)(srow + h);
        f32x4 a  = *(const f32x4*)(arow + h);
        f32x4 rl = *(const f32x4*)(relp + h);
        P += v.x * rl.x + v.y * rl.y + v.z * rl.z + v.w * rl.w;
        R += v.x * v.x + v.y * v.y + v.z * v.z + v.w * v.w;
        A += a.x * a.x + a.y * a.y + a.z * a.z + a.w * a.w;
        D += v.x * a.x + v.y * a.y + v.z * a.z + v.w * a.w;
        bf16x4 vb = { (__bf16)v.x, (__bf16)v.y, (__bf16)v.z, (__bf16)v.w };
        *(bf16x4*)(repb + rbase + h) = vb;
    }
    #pragma unroll
    for (int off = 32; off > 0; off >>= 1) {
        P += __shfl_xor(P, off, 64);
        R += __shfl_xor(R, off, 64);
        A += __shfl_xor(A, off, 64);
        D += __shfl_xor(D, off, 64);
    }
    if (lane == 0) {
        scoreg[row] = P * (1.0f / 32.0f);              // /sqrt(H)
        float nrv = sqrtf(R), nav = sqrtf(A);
        nr[row] = nrv;
        pos_sim[row] = D / fmaxf(nrv * nav, 1e-8f);
    }
}

// ---- kb: per-b softmax + bag from bf16 repb (L2/L3-hot) ----
__global__ __launch_bounds__(256) void kb(
    const __bf16* __restrict__ repb, const float* __restrict__ scoreg,
    __bf16* __restrict__ bagb, float* __restrict__ nbsq)
{
    __shared__ float alphaS[32];
    const int b = blockIdx.x, t = threadIdx.x;
    if (t < 32) {
        float sj = scoreg[b * 32 + t];
        float m = sj;
        #pragma unroll
        for (int off = 16; off > 0; off >>= 1) m = fmaxf(m, __shfl_xor(m, off, 32));
        float e = __expf(sj - m);
        float sum = e;
        #pragma unroll
        for (int off = 16; off > 0; off >>= 1) sum += __shfl_xor(sum, off, 32);
        alphaS[t] = e / sum;
    }
    __syncthreads();

    f32x4 acc = {};
    const __bf16* base = repb + (size_t)b * 32 * 1024 + t * 4;
    #pragma unroll 8
    for (int jj = 0; jj < 32; jj++) {
        bf16x4 v = *(const bf16x4*)(base + jj * 1024);
        const float al = alphaS[jj];
        acc.x += al * (float)v.x;
        acc.y += al * (float)v.y;
        acc.z += al * (float)v.z;
        acc.w += al * (float)v.w;
    }
    bf16x4 bb = { (__bf16)acc.x, (__bf16)acc.y, (__bf16)acc.z, (__bf16)acc.w };
    *(bf16x4*)(bagb + (size_t)b * 1024 + t * 4) = bb;

    float q = acc.x * acc.x + acc.y * acc.y + acc.z * acc.z + acc.w * acc.w;
    q = wsum(q);
    if ((t & 63) == 0) atomicAdd(&nbsq[b], q);
}

// ---- k3m: bag_out = bagb @ cwb^T + cls_b via MFMA, K-chunk 64, gll staging ----
__global__ __launch_bounds__(256) void k3m(
    const __bf16* __restrict__ bagb, const __bf16* __restrict__ cwb,
    const float* __restrict__ bias, float* __restrict__ out)
{
    __shared__ __align__(16) __bf16 Al[2 * 2048];      // two 64x32 sub-tiles
    __shared__ __align__(16) __bf16 Bl[2 * 2048];
    const int r0 = blockIdx.x * 64;                    // 8 blocks
    const int t = threadIdx.x, lane = t & 63, w = t >> 6;
    const int m = lane & 15, quad = lane >> 4;
    f32x4 acc[4] = {};

    const int i0 = t * 8;
    const int row0 = i0 >> 5, kk0 = i0 & 31;
    const __bf16* gA = bagb + (size_t)(r0 + row0) * 1024 + kk0;
    const __bf16* gB = cwb + (size_t)row0 * 1024 + kk0;

    for (int k0 = 0; k0 < 1024; k0 += 64) {
        __syncthreads();
        gll16(gA + k0,      Al + i0);
        gll16(gA + k0 + 32, Al + 2048 + i0);
        gll16(gB + k0,      Bl + i0);
        gll16(gB + k0 + 32, Bl + 2048 + i0);
        __syncthreads();
        #pragma unroll
        for (int ks = 0; ks < 2; ks++) {
            bf16x8 a = *(const bf16x8*)(&Al[ks * 2048 + (w * 16 + m) * 32 + quad * 8]);
            #pragma unroll
            for (int n = 0; n < 4; n++) {
                bf16x8 bf = *(const bf16x8*)(&Bl[ks * 2048 + (n * 16 + m) * 32 + quad * 8]);
                acc[n] = __builtin_amdgcn_mfma_f32_16x16x32_bf16(a, bf, acc[n], 0, 0, 0);
            }
        }
    }
    #pragma unroll
    for (int n = 0; n < 4; n++) {
        const int c = n * 16 + m;
        if (c < 53) {
            #pragma unroll
            for (int i = 0; i < 4; i++) {
                const int r = r0 + w * 16 + quad * 4 + i;
                out[(size_t)r * 53 + c] = acc[n][i] + bias[c];
            }
        }
    }
}

// ---- k4: MFMA 128x128 tile; fused exp + per-tile b-reduction -> partial[rb][32][512], diag ----
__global__ __launch_bounds__(256) void k4_gemm(
    const __bf16* __restrict__ repb, const __bf16* __restrict__ bagb,
    const float* __restrict__ nr, const float* __restrict__ nbsq,
    const float* __restrict__ temp, float* __restrict__ partial, float* __restrict__ diag)
{
    __shared__ __align__(16) __bf16 Al[128 * 32];      // [row][k], no pad
    __shared__ __align__(16) __bf16 Bl[128 * 32];
    __shared__ float negp[2][32][128];                 // 32 KB, unique-writer
    const int bid = blockIdx.x;
    const int xcd = bid & 7, slot = bid >> 3;
    const int cb = slot & 3, rb = (slot >> 2) * 8 + xcd;
    const int r0 = rb * 128, c0 = cb * 128;
    const int t = threadIdx.x, lane = t & 63, w = t >> 6;
    const int m = lane & 15, quad = lane >> 4;
    const int wr0 = (w & 1) * 64, wc0 = (w >> 1) * 64;
    const int half = w & 1;

    #pragma unroll
    for (int z = 0; z < 32; z++) ((float*)negp)[z * 256 + t] = 0.f;

    f32x4 acc[4][4] = {};

    const int i0 = t * 8, i1 = 2048 + t * 8;
    const int row0 = i0 >> 5, kk0 = i0 & 31;
    const int row1 = i1 >> 5, kk1 = i1 & 31;
    const __bf16* gA0 = repb + (size_t)(r0 + row0) * 1024 + kk0;
    const __bf16* gA1 = repb + (size_t)(r0 + row1) * 1024 + kk1;
    const __bf16* gB0 = bagb + (size_t)(c0 + row0) * 1024 + kk0;
    const __bf16* gB1 = bagb + (size_t)(c0 + row1) * 1024 + kk1;

    for (int k0 = 0; k0 < 1024; k0 += 32) {
        __syncthreads();
        gll16(gA0 + k0, Al + i0);
        gll16(gA1 + k0, Al + i1);
        gll16(gB0 + k0, Bl + i0);
        gll16(gB1 + k0, Bl + i1);
        __syncthreads();
        bf16x8 a[4], bf[4];
        #pragma unroll
        for (int i = 0; i < 4; i++) a[i]  = *(const bf16x8*)(&Al[(wr0 + i * 16 + m) * 32 + quad * 8]);
        #pragma unroll
        for (int n = 0; n < 4; n++) bf[n] = *(const bf16x8*)(&Bl[(wc0 + n * 16 + m) * 32 + quad * 8]);
        #pragma unroll
        for (int i = 0; i < 4; i++)
            #pragma unroll
            for (int n = 0; n < 4; n++)
                acc[i][n] = __builtin_amdgcn_mfma_f32_16x16x32_bf16(a[i], bf[n], acc[i][n], 0, 0, 0);
    }

    const float invT = 1.0f / *temp;
    float nrv[16];
    #pragma unroll
    for (int i = 0; i < 4; i++)
        #pragma unroll
        for (int g = 0; g < 4; g++)
            nrv[i * 4 + g] = nr[r0 + wr0 + i * 16 + quad * 4 + g];

    #pragma unroll
    for (int n = 0; n < 4; n++) {
        const int c_local = wc0 + n * 16 + m;
        const int cg = c0 + c_local;
        const float nbv = sqrtf(nbsq[cg]);
        #pragma unroll
        for (int i = 0; i < 2; i++) {                  // parity pairs (i, i+2)
            #pragma unroll
            for (int g = 0; g < 4; g++) {
                const int jj = i * 16 + quad * 4 + g;
                const int rg0 = r0 + wr0 + i * 16 + quad * 4 + g;
                const int rg2 = rg0 + 32;
                float e0 = __expf(acc[i][n][g]     / fmaxf(nbv * nrv[i * 4 + g],       1e-8f) * invT);
                float e2 = __expf(acc[i + 2][n][g] / fmaxf(nbv * nrv[(i + 2) * 4 + g], 1e-8f) * invT);
                negp[half][jj][c_local] = e0 + e2;
                if ((rg0 >> 5) == cg) diag[(size_t)cg * 32 + jj] = e0;
                if ((rg2 >> 5) == cg) diag[(size_t)cg * 32 + jj] = e2;
            }
        }
    }
    __syncthreads();

    float* pout = partial + (size_t)rb * 32 * 512 + c0;
    #pragma unroll
    for (int v = 0; v < 4; v++) {
        const int idx = v * 1024 + t * 4;              // 0..4095
        const int jj = idx >> 7, cl = idx & 127;
        f32x4 a = *(const f32x4*)(&negp[0][jj][cl]);
        f32x4 bq = *(const f32x4*)(&negp[1][jj][cl]);
        f32x4 s = a + bq;
        *(f32x4*)(pout + (size_t)jj * 512 + cl) = s;
    }
}

// ---- k5: reduce partial over rb (128) + loss terms; 256 blocks ----
__global__ __launch_bounds__(256) void k5_neg(
    const float* __restrict__ partial, const float* __restrict__ diag,
    const float* __restrict__ pos_sim, const float* __restrict__ temp,
    float* __restrict__ bsums)
{
    const int ct = blockIdx.x & 7, j = blockIdx.x >> 3;
    const int t = threadIdx.x, lane = t & 63, w = t >> 6;
    const int bsub = t >> 4;                           // 0..15 (rb-group of 8)
    const int cidx = t & 15;                           // x4 cols
    f32x4 acc = {};
    #pragma unroll 4
    for (int r = 0; r < 8; r++) {
        const int rb = bsub * 8 + r;
        f32x4 v = *(const f32x4*)(partial + ((size_t)rb * 32 + j) * 512 + ct * 64 + cidx * 4);
        acc += v;
    }
    #pragma unroll
    for (int k = 0; k < 4; k++) {
        acc[k] += __shfl_xor(acc[k], 16, 64);
        acc[k] += __shfl_xor(acc[k], 32, 64);
    }
    __shared__ float red[4][64];
    if (lane < 16) {
        #pragma unroll
        for (int k = 0; k < 4; k++) red[w][lane * 4 + k] = acc[k];
    }
    __syncthreads();

    if (t < 64) {
        const int c = ct * 64 + t;
        float S = red[0][t] + red[1][t] + red[2][t] + red[3][t];
        S -= diag[(size_t)c * 32 + j];                 // near-exact cancellation (f32)
        const float invT = 1.0f / *temp;
        const float lp = pos_sim[(c << 5) + j] * invT;
        float term = logf(__expf(lp) + S) - lp;
        term = wsum(term);
        if (t == 0) bsums[blockIdx.x] = term;
    }
}

__global__ __launch_bounds__(256) void k6_final(const float* __restrict__ bsums, float* __restrict__ loss)
{
    const int t = threadIdx.x;
    float v = bsums[t];
    v = wsum(v);
    __shared__ float r[4];
    if ((t & 63) == 0) r[t >> 6] = v;
    __syncthreads();
    if (t == 0) *loss = (r[0] + r[1] + r[2] + r[3]) * (1.0f / 16384.0f);
}

extern "C" void kernel_launch(void* const* d_in, const int* in_sizes, int n_in,
                              void* d_out, int out_size, void* d_ws, size_t ws_size,
                              hipStream_t stream)
{
    const float* sent = (const float*)d_in[0];
    const float* aug  = (const float*)d_in[1];
    const float* rel  = (const float*)d_in[2];
    const float* clsw = (const float*)d_in[3];
    const float* clsb = (const float*)d_in[4];
    const int*   lab  = (const int*)d_in[5];
    const float* temp = (const float*)d_in[6];
    float* out = (float*)d_out;

    char* ws = (char*)d_ws;
    __bf16* bagb    = (__bf16*)(ws);                           // 1 MB
    float*  nbsq    = (float*)(ws + (1u << 20));               // 2 KB
    float*  nr      = (float*)(ws + (1u << 20) + 64 * 1024);   // 64 KB
    float*  pos     = (float*)(ws + (1u << 20) + 128 * 1024);  // 64 KB
    __bf16* cwb     = (__bf16*)(ws + (1u << 20) + 192 * 1024); // 128 KB
    float*  scoreg  = (float*)(ws + (1u << 20) + 320 * 1024);  // 64 KB
    float*  bsums   = (float*)(ws + (2u << 20));               // 1 KB
    float*  diag    = (float*)(ws + (2u << 20) + 64 * 1024);   // 64 KB
    __bf16* repb    = (__bf16*)(ws + (4u << 20));              // 32 MB
    float*  partial = (float*)(ws + (36u << 20));              // 8 MB

    k0_cvt  <<<256, 256, 0, stream>>>(clsw, cwb, nbsq);
    ka      <<<4096, 256, 0, stream>>>(sent, aug, rel, lab, repb, nr, pos, scoreg);
    kb      <<<512, 256, 0, stream>>>(repb, scoreg, bagb, nbsq);
    k3m     <<<8, 256, 0, stream>>>(bagb, cwb, clsb, out);
    k4_gemm <<<512, 256, 0, stream>>>(repb, bagb, nr, nbsq, temp, partial, diag);
    k5_neg  <<<256, 256, 0, stream>>>(partial, diag, pos, temp, bsums);
    k6_final<<<1, 256, 0, stream>>>(bsums, out + 27136);
}

// Round 7
// 213.651 us; speedup vs baseline: 1.2533x; 1.0019x over previous
//
#include <hip/hip_runtime.h>
#include <hip/hip_bf16.h>

// Shapes: B=512, BAG=32, H=1024, C=53.  EPS=1e-8, scale=sqrt(1024)=32.
// Out: bag_out (512*53=27136) f32, then cl_loss scalar -> 27137 floats.

typedef __bf16 bf16x8 __attribute__((ext_vector_type(8)));
typedef __bf16 bf16x4 __attribute__((ext_vector_type(4)));
typedef float  f32x4  __attribute__((ext_vector_type(4)));

__device__ inline float wsum(float v) {
    #pragma unroll
    for (int off = 32; off > 0; off >>= 1) v += __shfl_xor(v, off, 64);
    return v;
}

__device__ inline void gll16(const void* g, void* l) {
    __builtin_amdgcn_global_load_lds((const __attribute__((address_space(1))) void*)g,
                                     (__attribute__((address_space(3))) void*)l, 16, 0, 0);
}

// ---- ka: streaming pass (2 rows/wave) + folded k0 (cls_w cvt, zero nbsq/loss) ----
__global__ __launch_bounds__(256) void ka(
    const float* __restrict__ sent, const float* __restrict__ aug,
    const float* __restrict__ rel_table, const int* __restrict__ labels,
    __bf16* __restrict__ repb, float* __restrict__ nr, float* __restrict__ pos_sim,
    float* __restrict__ scoreg,
    const float* __restrict__ clsw, __bf16* __restrict__ cwb,
    float* __restrict__ nbsq, float* __restrict__ loss)
{
    const int t = threadIdx.x;
    // folded k0: blocks 0..255 convert cls_w (padded to 64 rows); block 256 zeroes scalars
    if (blockIdx.x < 256) {
        const int i = blockIdx.x * 256 + t;
        cwb[i] = (i < 53 * 1024) ? (__bf16)clsw[i] : (__bf16)0.0f;
    } else if (blockIdx.x == 256) {
        nbsq[t] = 0.0f; nbsq[256 + t] = 0.0f;
        if (t == 0) *loss = 0.0f;
    }

    const int w = t >> 6, lane = t & 63;
    const int rp = blockIdx.x * 8 + w * 2;             // even row; rp,rp+1 share b
    const size_t rb0 = (size_t)rp * 1024, rb1 = rb0 + 1024;
    const float* s0 = sent + rb0;
    const float* s1 = sent + rb1;
    const float* a0 = aug + rb0;
    const float* a1 = aug + rb1;
    const float* relp = rel_table + (size_t)labels[rp >> 5] * 1024;

    f32x4 v0[4], v1[4], x0[4], x1[4], rl[4];
    #pragma unroll
    for (int i = 0; i < 4; i++) {
        const int h = i * 256 + lane * 4;
        v0[i] = *(const f32x4*)(s0 + h);
        v1[i] = *(const f32x4*)(s1 + h);
        x0[i] = *(const f32x4*)(a0 + h);
        x1[i] = *(const f32x4*)(a1 + h);
        rl[i] = *(const f32x4*)(relp + h);
    }
    float P0 = 0.f, R0 = 0.f, A0 = 0.f, D0 = 0.f;
    float P1 = 0.f, R1 = 0.f, A1 = 0.f, D1 = 0.f;
    #pragma unroll
    for (int i = 0; i < 4; i++) {
        const int h = i * 256 + lane * 4;
        #pragma unroll
        for (int e = 0; e < 4; e++) {
            P0 += v0[i][e] * rl[i][e];  R0 += v0[i][e] * v0[i][e];
            A0 += x0[i][e] * x0[i][e];  D0 += v0[i][e] * x0[i][e];
            P1 += v1[i][e] * rl[i][e];  R1 += v1[i][e] * v1[i][e];
            A1 += x1[i][e] * x1[i][e];  D1 += v1[i][e] * x1[i][e];
        }
        bf16x4 w0 = { (__bf16)v0[i][0], (__bf16)v0[i][1], (__bf16)v0[i][2], (__bf16)v0[i][3] };
        bf16x4 w1 = { (__bf16)v1[i][0], (__bf16)v1[i][1], (__bf16)v1[i][2], (__bf16)v1[i][3] };
        *(bf16x4*)(repb + rb0 + h) = w0;
        *(bf16x4*)(repb + rb1 + h) = w1;
    }
    #pragma unroll
    for (int off = 32; off > 0; off >>= 1) {
        P0 += __shfl_xor(P0, off, 64); R0 += __shfl_xor(R0, off, 64);
        A0 += __shfl_xor(A0, off, 64); D0 += __shfl_xor(D0, off, 64);
        P1 += __shfl_xor(P1, off, 64); R1 += __shfl_xor(R1, off, 64);
        A1 += __shfl_xor(A1, off, 64); D1 += __shfl_xor(D1, off, 64);
    }
    if (lane == 0) {
        scoreg[rp]     = P0 * (1.0f / 32.0f);
        scoreg[rp + 1] = P1 * (1.0f / 32.0f);
        float n0 = sqrtf(R0), m0 = sqrtf(A0);
        float n1 = sqrtf(R1), m1 = sqrtf(A1);
        nr[rp] = n0; nr[rp + 1] = n1;
        pos_sim[rp]     = D0 / fmaxf(n0 * m0, 1e-8f);
        pos_sim[rp + 1] = D1 / fmaxf(n1 * m1, 1e-8f);
    }
}

// ---- kb: per-b softmax + bag from bf16 repb (L2/L3-hot) ----
__global__ __launch_bounds__(256) void kb(
    const __bf16* __restrict__ repb, const float* __restrict__ scoreg,
    __bf16* __restrict__ bagb, float* __restrict__ nbsq)
{
    __shared__ float alphaS[32];
    const int b = blockIdx.x, t = threadIdx.x;
    if (t < 32) {
        float sj = scoreg[b * 32 + t];
        float m = sj;
        #pragma unroll
        for (int off = 16; off > 0; off >>= 1) m = fmaxf(m, __shfl_xor(m, off, 32));
        float e = __expf(sj - m);
        float sum = e;
        #pragma unroll
        for (int off = 16; off > 0; off >>= 1) sum += __shfl_xor(sum, off, 32);
        alphaS[t] = e / sum;
    }
    __syncthreads();

    f32x4 acc = {};
    const __bf16* base = repb + (size_t)b * 32 * 1024 + t * 4;
    #pragma unroll 8
    for (int jj = 0; jj < 32; jj++) {
        bf16x4 v = *(const bf16x4*)(base + jj * 1024);
        const float al = alphaS[jj];
        acc.x += al * (float)v.x;
        acc.y += al * (float)v.y;
        acc.z += al * (float)v.z;
        acc.w += al * (float)v.w;
    }
    bf16x4 bb = { (__bf16)acc.x, (__bf16)acc.y, (__bf16)acc.z, (__bf16)acc.w };
    *(bf16x4*)(bagb + (size_t)b * 1024 + t * 4) = bb;

    float q = acc.x * acc.x + acc.y * acc.y + acc.z * acc.z + acc.w * acc.w;
    q = wsum(q);
    if ((t & 63) == 0) atomicAdd(&nbsq[b], q);
}

// ---- k4: MFMA 128x128 tile (blocks 0..511) + folded k3m classifier (blocks 512..519) ----
__global__ __launch_bounds__(256) void k4_gemm(
    const __bf16* __restrict__ repb, const __bf16* __restrict__ bagb,
    const float* __restrict__ nr, const float* __restrict__ nbsq,
    const float* __restrict__ temp, float* __restrict__ partial, float* __restrict__ diag,
    const __bf16* __restrict__ cwb, const float* __restrict__ bias, float* __restrict__ out)
{
    __shared__ __align__(16) char smem[49152];         // 48 KB: Al 8K | Bl 8K | negp 32K
    __bf16* Al = (__bf16*)smem;
    __bf16* Bl = (__bf16*)(smem + 8192);
    const int bid = blockIdx.x;
    const int t = threadIdx.x, lane = t & 63, w = t >> 6;
    const int m = lane & 15, quad = lane >> 4;

    if (bid >= 512) {
        // ---- folded k3m: bag_out = bagb @ cwb^T + cls_b ----
        const int r0 = (bid - 512) * 64;
        f32x4 acc[4] = {};
        const int i0 = t * 8;
        const int row0 = i0 >> 5, kk0 = i0 & 31;
        const __bf16* gA = bagb + (size_t)(r0 + row0) * 1024 + kk0;
        const __bf16* gB = cwb + (size_t)row0 * 1024 + kk0;
        for (int k0 = 0; k0 < 1024; k0 += 64) {
            __syncthreads();
            gll16(gA + k0,      Al + i0);
            gll16(gA + k0 + 32, Al + 2048 + i0);
            gll16(gB + k0,      Bl + i0);
            gll16(gB + k0 + 32, Bl + 2048 + i0);
            __syncthreads();
            #pragma unroll
            for (int ks = 0; ks < 2; ks++) {
                bf16x8 a = *(const bf16x8*)(&Al[ks * 2048 + (w * 16 + m) * 32 + quad * 8]);
                #pragma unroll
                for (int n = 0; n < 4; n++) {
                    bf16x8 bf = *(const bf16x8*)(&Bl[ks * 2048 + (n * 16 + m) * 32 + quad * 8]);
                    acc[n] = __builtin_amdgcn_mfma_f32_16x16x32_bf16(a, bf, acc[n], 0, 0, 0);
                }
            }
        }
        #pragma unroll
        for (int n = 0; n < 4; n++) {
            const int c = n * 16 + m;
            if (c < 53) {
                #pragma unroll
                for (int i = 0; i < 4; i++) {
                    const int r = r0 + w * 16 + quad * 4 + i;
                    out[(size_t)r * 53 + c] = acc[n][i] + bias[c];
                }
            }
        }
        return;
    }

    float (*negp)[32][128] = (float (*)[32][128])(smem + 16384);
    const int xcd = bid & 7, slot = bid >> 3;
    const int cb = slot & 3, rb = (slot >> 2) * 8 + xcd;
    const int r0 = rb * 128, c0 = cb * 128;
    const int wr0 = (w & 1) * 64, wc0 = (w >> 1) * 64;
    const int half = w & 1;

    #pragma unroll
    for (int z = 0; z < 32; z++) ((float*)negp)[z * 256 + t] = 0.f;

    f32x4 acc[4][4] = {};

    const int i0 = t * 8, i1 = 2048 + t * 8;
    const int row0 = i0 >> 5, kk0 = i0 & 31;
    const int row1 = i1 >> 5, kk1 = i1 & 31;
    const __bf16* gA0 = repb + (size_t)(r0 + row0) * 1024 + kk0;
    const __bf16* gA1 = repb + (size_t)(r0 + row1) * 1024 + kk1;
    const __bf16* gB0 = bagb + (size_t)(c0 + row0) * 1024 + kk0;
    const __bf16* gB1 = bagb + (size_t)(c0 + row1) * 1024 + kk1;

    for (int k0 = 0; k0 < 1024; k0 += 32) {
        __syncthreads();
        gll16(gA0 + k0, Al + i0);
        gll16(gA1 + k0, Al + i1);
        gll16(gB0 + k0, Bl + i0);
        gll16(gB1 + k0, Bl + i1);
        __syncthreads();
        bf16x8 a[4], bf[4];
        #pragma unroll
        for (int i = 0; i < 4; i++) a[i]  = *(const bf16x8*)(&Al[(wr0 + i * 16 + m) * 32 + quad * 8]);
        #pragma unroll
        for (int n = 0; n < 4; n++) bf[n] = *(const bf16x8*)(&Bl[(wc0 + n * 16 + m) * 32 + quad * 8]);
        #pragma unroll
        for (int i = 0; i < 4; i++)
            #pragma unroll
            for (int n = 0; n < 4; n++)
                acc[i][n] = __builtin_amdgcn_mfma_f32_16x16x32_bf16(a[i], bf[n], acc[i][n], 0, 0, 0);
    }

    const float invT = 1.0f / *temp;
    float nrv[16];
    #pragma unroll
    for (int i = 0; i < 4; i++)
        #pragma unroll
        for (int g = 0; g < 4; g++)
            nrv[i * 4 + g] = nr[r0 + wr0 + i * 16 + quad * 4 + g];

    #pragma unroll
    for (int n = 0; n < 4; n++) {
        const int c_local = wc0 + n * 16 + m;
        const int cg = c0 + c_local;
        const float nbv = sqrtf(nbsq[cg]);
        #pragma unroll
        for (int i = 0; i < 2; i++) {                  // parity pairs (i, i+2)
            #pragma unroll
            for (int g = 0; g < 4; g++) {
                const int jj = i * 16 + quad * 4 + g;
                const int rg0 = r0 + wr0 + i * 16 + quad * 4 + g;
                const int rg2 = rg0 + 32;
                float e0 = __expf(acc[i][n][g]     / fmaxf(nbv * nrv[i * 4 + g],       1e-8f) * invT);
                float e2 = __expf(acc[i + 2][n][g] / fmaxf(nbv * nrv[(i + 2) * 4 + g], 1e-8f) * invT);
                negp[half][jj][c_local] = e0 + e2;
                if ((rg0 >> 5) == cg) diag[(size_t)cg * 32 + jj] = e0;
                if ((rg2 >> 5) == cg) diag[(size_t)cg * 32 + jj] = e2;
            }
        }
    }
    __syncthreads();

    float* pout = partial + (size_t)rb * 32 * 512 + c0;
    #pragma unroll
    for (int v = 0; v < 4; v++) {
        const int idx = v * 1024 + t * 4;              // 0..4095
        const int jj = idx >> 7, cl = idx & 127;
        f32x4 a = *(const f32x4*)(&negp[0][jj][cl]);
        f32x4 bq = *(const f32x4*)(&negp[1][jj][cl]);
        f32x4 s = a + bq;
        *(f32x4*)(pout + (size_t)jj * 512 + cl) = s;
    }
}

// ---- k5: reduce partial over rb (128) + loss terms; atomic accumulate into loss ----
__global__ __launch_bounds__(256) void k5_neg(
    const float* __restrict__ partial, const float* __restrict__ diag,
    const float* __restrict__ pos_sim, const float* __restrict__ temp,
    float* __restrict__ loss)
{
    const int ct = blockIdx.x & 7, j = blockIdx.x >> 3;
    const int t = threadIdx.x, lane = t & 63, w = t >> 6;
    const int bsub = t >> 4;                           // 0..15 (rb-group of 8)
    const int cidx = t & 15;                           // x4 cols
    f32x4 acc = {};
    #pragma unroll 4
    for (int r = 0; r < 8; r++) {
        const int rb = bsub * 8 + r;
        f32x4 v = *(const f32x4*)(partial + ((size_t)rb * 32 + j) * 512 + ct * 64 + cidx * 4);
        acc += v;
    }
    #pragma unroll
    for (int k = 0; k < 4; k++) {
        acc[k] += __shfl_xor(acc[k], 16, 64);
        acc[k] += __shfl_xor(acc[k], 32, 64);
    }
    __shared__ float red[4][64];
    if (lane < 16) {
        #pragma unroll
        for (int k = 0; k < 4; k++) red[w][lane * 4 + k] = acc[k];
    }
    __syncthreads();

    if (t < 64) {
        const int c = ct * 64 + t;
        float S = red[0][t] + red[1][t] + red[2][t] + red[3][t];
        S -= diag[(size_t)c * 32 + j];                 // near-exact cancellation (f32)
        const float invT = 1.0f / *temp;
        const float lp = pos_sim[(c << 5) + j] * invT;
        float term = logf(__expf(lp) + S) - lp;
        term = wsum(term);
        if (t == 0) atomicAdd(loss, term * (1.0f / 16384.0f));
    }
}

extern "C" void kernel_launch(void* const* d_in, const int* in_sizes, int n_in,
                              void* d_out, int out_size, void* d_ws, size_t ws_size,
                              hipStream_t stream)
{
    const float* sent = (const float*)d_in[0];
    const float* aug  = (const float*)d_in[1];
    const float* rel  = (const float*)d_in[2];
    const float* clsw = (const float*)d_in[3];
    const float* clsb = (const float*)d_in[4];
    const int*   lab  = (const int*)d_in[5];
    const float* temp = (const float*)d_in[6];
    float* out = (float*)d_out;

    char* ws = (char*)d_ws;
    __bf16* bagb    = (__bf16*)(ws);                           // 1 MB
    float*  nbsq    = (float*)(ws + (1u << 20));               // 2 KB
    float*  nr      = (float*)(ws + (1u << 20) + 64 * 1024);   // 64 KB
    float*  pos     = (float*)(ws + (1u << 20) + 128 * 1024);  // 64 KB
    __bf16* cwb     = (__bf16*)(ws + (1u << 20) + 192 * 1024); // 128 KB
    float*  scoreg  = (float*)(ws + (1u << 20) + 320 * 1024);  // 64 KB
    float*  diag    = (float*)(ws + (2u << 20) + 64 * 1024);   // 64 KB
    __bf16* repb    = (__bf16*)(ws + (4u << 20));              // 32 MB
    float*  partial = (float*)(ws + (36u << 20));              // 8 MB

    float* loss = out + 27136;

    ka     <<<2048, 256, 0, stream>>>(sent, aug, rel, lab, repb, nr, pos, scoreg,
                                      clsw, cwb, nbsq, loss);
    kb     <<<512, 256, 0, stream>>>(repb, scoreg, bagb, nbsq);
    k4_gemm<<<520, 256, 0, stream>>>(repb, bagb, nr, nbsq, temp, partial, diag,
                                     cwb, clsb, out);
    k5_neg <<<256, 256, 0, stream>>>(partial, diag, pos, temp, loss);
}

// Round 8
// 202.602 us; speedup vs baseline: 1.3217x; 1.0545x over previous
//
#include <hip/hip_runtime.h>
#include <hip/hip_bf16.h>

// Shapes: B=512, BAG=32, H=1024, C=53.  EPS=1e-8, scale=sqrt(1024)=32.
// Out: bag_out (512*53=27136) f32, then cl_loss scalar -> 27137 floats.

typedef __bf16 bf16x8 __attribute__((ext_vector_type(8)));
typedef __bf16 bf16x4 __attribute__((ext_vector_type(4)));
typedef float  f32x4  __attribute__((ext_vector_type(4)));

__device__ inline float wsum(float v) {
    #pragma unroll
    for (int off = 32; off > 0; off >>= 1) v += __shfl_xor(v, off, 64);
    return v;
}

__device__ inline void gll16(const void* g, void* l) {
    __builtin_amdgcn_global_load_lds((const __attribute__((address_space(1))) void*)g,
                                     (__attribute__((address_space(3))) void*)l, 16, 0, 0);
}

__device__ inline f32x4 ntld(const float* p) {
    return __builtin_nontemporal_load((const f32x4*)p);
}

// ---- ka: streaming pass (1 row/wave, NT input loads) + folded k0 ----
__global__ __launch_bounds__(256) void ka(
    const float* __restrict__ sent, const float* __restrict__ aug,
    const float* __restrict__ rel_table, const int* __restrict__ labels,
    __bf16* __restrict__ repb, float* __restrict__ nr, float* __restrict__ pos_sim,
    float* __restrict__ scoreg,
    const float* __restrict__ clsw, __bf16* __restrict__ cwb,
    float* __restrict__ nbsq, float* __restrict__ loss)
{
    const int t = threadIdx.x;
    // folded k0: blocks 0..255 convert cls_w (padded to 64 rows); block 256 zeroes scalars
    if (blockIdx.x < 256) {
        const int i = blockIdx.x * 256 + t;
        cwb[i] = (i < 53 * 1024) ? (__bf16)clsw[i] : (__bf16)0.0f;
    } else if (blockIdx.x == 256) {
        nbsq[t] = 0.0f; nbsq[256 + t] = 0.0f;
        if (t == 0) *loss = 0.0f;
    }

    const int w = t >> 6, lane = t & 63;
    const int row = blockIdx.x * 4 + w;                // 0..16383 (wave-uniform)
    const int b = row >> 5;
    const size_t rbase = (size_t)row * 1024;
    const float* srow = sent + rbase;
    const float* arow = aug + rbase;
    const float* relp = rel_table + (size_t)labels[b] * 1024;

    float P = 0.f, R = 0.f, A = 0.f, D = 0.f;
    #pragma unroll
    for (int i = 0; i < 4; i++) {
        const int h = i * 256 + lane * 4;
        f32x4 v  = ntld(srow + h);                     // nt: read-once, don't pollute L3
        f32x4 a  = ntld(arow + h);
        f32x4 rl = *(const f32x4*)(relp + h);          // reused across bags: keep cached
        P += v.x * rl.x + v.y * rl.y + v.z * rl.z + v.w * rl.w;
        R += v.x * v.x + v.y * v.y + v.z * v.z + v.w * v.w;
        A += a.x * a.x + a.y * a.y + a.z * a.z + a.w * a.w;
        D += v.x * a.x + v.y * a.y + v.z * a.z + v.w * a.w;
        bf16x4 vb = { (__bf16)v.x, (__bf16)v.y, (__bf16)v.z, (__bf16)v.w };
        *(bf16x4*)(repb + rbase + h) = vb;
    }
    #pragma unroll
    for (int off = 32; off > 0; off >>= 1) {
        P += __shfl_xor(P, off, 64);
        R += __shfl_xor(R, off, 64);
        A += __shfl_xor(A, off, 64);
        D += __shfl_xor(D, off, 64);
    }
    if (lane == 0) {
        scoreg[row] = P * (1.0f / 32.0f);              // /sqrt(H)
        float nrv = sqrtf(R), nav = sqrtf(A);
        nr[row] = nrv;
        pos_sim[row] = D / fmaxf(nrv * nav, 1e-8f);
    }
}

// ---- kb: per-b softmax + bag from bf16 repb (L2/L3-hot) ----
__global__ __launch_bounds__(256) void kb(
    const __bf16* __restrict__ repb, const float* __restrict__ scoreg,
    __bf16* __restrict__ bagb, float* __restrict__ nbsq)
{
    __shared__ float alphaS[32];
    const int b = blockIdx.x, t = threadIdx.x;
    if (t < 32) {
        float sj = scoreg[b * 32 + t];
        float m = sj;
        #pragma unroll
        for (int off = 16; off > 0; off >>= 1) m = fmaxf(m, __shfl_xor(m, off, 32));
        float e = __expf(sj - m);
        float sum = e;
        #pragma unroll
        for (int off = 16; off > 0; off >>= 1) sum += __shfl_xor(sum, off, 32);
        alphaS[t] = e / sum;
    }
    __syncthreads();

    f32x4 acc = {};
    const __bf16* base = repb + (size_t)b * 32 * 1024 + t * 4;
    #pragma unroll 8
    for (int jj = 0; jj < 32; jj++) {
        bf16x4 v = *(const bf16x4*)(base + jj * 1024);
        const float al = alphaS[jj];
        acc.x += al * (float)v.x;
        acc.y += al * (float)v.y;
        acc.z += al * (float)v.z;
        acc.w += al * (float)v.w;
    }
    bf16x4 bb = { (__bf16)acc.x, (__bf16)acc.y, (__bf16)acc.z, (__bf16)acc.w };
    *(bf16x4*)(bagb + (size_t)b * 1024 + t * 4) = bb;

    float q = acc.x * acc.x + acc.y * acc.y + acc.z * acc.z + acc.w * acc.w;
    q = wsum(q);
    if ((t & 63) == 0) atomicAdd(&nbsq[b], q);
}

// ---- k4: MFMA 128x128 tile (blocks 0..511) + folded k3m classifier (blocks 512..519) ----
__global__ __launch_bounds__(256) void k4_gemm(
    const __bf16* __restrict__ repb, const __bf16* __restrict__ bagb,
    const float* __restrict__ nr, const float* __restrict__ nbsq,
    const float* __restrict__ temp, float* __restrict__ partial, float* __restrict__ diag,
    const __bf16* __restrict__ cwb, const float* __restrict__ bias, float* __restrict__ out)
{
    __shared__ __align__(16) char smem[49152];         // 48 KB: Al 8K | Bl 8K | negp 32K
    __bf16* Al = (__bf16*)smem;
    __bf16* Bl = (__bf16*)(smem + 8192);
    const int bid = blockIdx.x;
    const int t = threadIdx.x, lane = t & 63, w = t >> 6;
    const int m = lane & 15, quad = lane >> 4;

    if (bid >= 512) {
        // ---- folded k3m: bag_out = bagb @ cwb^T + cls_b ----
        const int r0 = (bid - 512) * 64;
        f32x4 acc[4] = {};
        const int i0 = t * 8;
        const int row0 = i0 >> 5, kk0 = i0 & 31;
        const __bf16* gA = bagb + (size_t)(r0 + row0) * 1024 + kk0;
        const __bf16* gB = cwb + (size_t)row0 * 1024 + kk0;
        for (int k0 = 0; k0 < 1024; k0 += 64) {
            __syncthreads();
            gll16(gA + k0,      Al + i0);
            gll16(gA + k0 + 32, Al + 2048 + i0);
            gll16(gB + k0,      Bl + i0);
            gll16(gB + k0 + 32, Bl + 2048 + i0);
            __syncthreads();
            #pragma unroll
            for (int ks = 0; ks < 2; ks++) {
                bf16x8 a = *(const bf16x8*)(&Al[ks * 2048 + (w * 16 + m) * 32 + quad * 8]);
                #pragma unroll
                for (int n = 0; n < 4; n++) {
                    bf16x8 bf = *(const bf16x8*)(&Bl[ks * 2048 + (n * 16 + m) * 32 + quad * 8]);
                    acc[n] = __builtin_amdgcn_mfma_f32_16x16x32_bf16(a, bf, acc[n], 0, 0, 0);
                }
            }
        }
        #pragma unroll
        for (int n = 0; n < 4; n++) {
            const int c = n * 16 + m;
            if (c < 53) {
                #pragma unroll
                for (int i = 0; i < 4; i++) {
                    const int r = r0 + w * 16 + quad * 4 + i;
                    out[(size_t)r * 53 + c] = acc[n][i] + bias[c];
                }
            }
        }
        return;
    }

    float (*negp)[32][128] = (float (*)[32][128])(smem + 16384);
    const int xcd = bid & 7, slot = bid >> 3;
    const int cb = slot & 3, rb = (slot >> 2) * 8 + xcd;
    const int r0 = rb * 128, c0 = cb * 128;
    const int wr0 = (w & 1) * 64, wc0 = (w >> 1) * 64;
    const int half = w & 1;

    #pragma unroll
    for (int z = 0; z < 32; z++) ((float*)negp)[z * 256 + t] = 0.f;

    f32x4 acc[4][4] = {};

    const int i0 = t * 8, i1 = 2048 + t * 8;
    const int row0 = i0 >> 5, kk0 = i0 & 31;
    const int row1 = i1 >> 5, kk1 = i1 & 31;
    const __bf16* gA0 = repb + (size_t)(r0 + row0) * 1024 + kk0;
    const __bf16* gA1 = repb + (size_t)(r0 + row1) * 1024 + kk1;
    const __bf16* gB0 = bagb + (size_t)(c0 + row0) * 1024 + kk0;
    const __bf16* gB1 = bagb + (size_t)(c0 + row1) * 1024 + kk1;

    for (int k0 = 0; k0 < 1024; k0 += 32) {
        __syncthreads();
        gll16(gA0 + k0, Al + i0);
        gll16(gA1 + k0, Al + i1);
        gll16(gB0 + k0, Bl + i0);
        gll16(gB1 + k0, Bl + i1);
        __syncthreads();
        bf16x8 a[4], bf[4];
        #pragma unroll
        for (int i = 0; i < 4; i++) a[i]  = *(const bf16x8*)(&Al[(wr0 + i * 16 + m) * 32 + quad * 8]);
        #pragma unroll
        for (int n = 0; n < 4; n++) bf[n] = *(const bf16x8*)(&Bl[(wc0 + n * 16 + m) * 32 + quad * 8]);
        #pragma unroll
        for (int i = 0; i < 4; i++)
            #pragma unroll
            for (int n = 0; n < 4; n++)
                acc[i][n] = __builtin_amdgcn_mfma_f32_16x16x32_bf16(a[i], bf[n], acc[i][n], 0, 0, 0);
    }

    const float invT = 1.0f / *temp;
    float nrv[16];
    #pragma unroll
    for (int i = 0; i < 4; i++)
        #pragma unroll
        for (int g = 0; g < 4; g++)
            nrv[i * 4 + g] = nr[r0 + wr0 + i * 16 + quad * 4 + g];

    #pragma unroll
    for (int n = 0; n < 4; n++) {
        const int c_local = wc0 + n * 16 + m;
        const int cg = c0 + c_local;
        const float nbv = sqrtf(nbsq[cg]);
        #pragma unroll
        for (int i = 0; i < 2; i++) {                  // parity pairs (i, i+2)
            #pragma unroll
            for (int g = 0; g < 4; g++) {
                const int jj = i * 16 + quad * 4 + g;
                const int rg0 = r0 + wr0 + i * 16 + quad * 4 + g;
                const int rg2 = rg0 + 32;
                float e0 = __expf(acc[i][n][g]     / fmaxf(nbv * nrv[i * 4 + g],       1e-8f) * invT);
                float e2 = __expf(acc[i + 2][n][g] / fmaxf(nbv * nrv[(i + 2) * 4 + g], 1e-8f) * invT);
                negp[half][jj][c_local] = e0 + e2;
                if ((rg0 >> 5) == cg) diag[(size_t)cg * 32 + jj] = e0;
                if ((rg2 >> 5) == cg) diag[(size_t)cg * 32 + jj] = e2;
            }
        }
    }
    __syncthreads();

    float* pout = partial + (size_t)rb * 32 * 512 + c0;
    #pragma unroll
    for (int v = 0; v < 4; v++) {
        const int idx = v * 1024 + t * 4;              // 0..4095
        const int jj = idx >> 7, cl = idx & 127;
        f32x4 a = *(const f32x4*)(&negp[0][jj][cl]);
        f32x4 bq = *(const f32x4*)(&negp[1][jj][cl]);
        f32x4 s = a + bq;
        *(f32x4*)(pout + (size_t)jj * 512 + cl) = s;
    }
}

// ---- k5: reduce partial over rb (128) + loss terms; atomic accumulate into loss ----
__global__ __launch_bounds__(256) void k5_neg(
    const float* __restrict__ partial, const float* __restrict__ diag,
    const float* __restrict__ pos_sim, const float* __restrict__ temp,
    float* __restrict__ loss)
{
    const int ct = blockIdx.x & 7, j = blockIdx.x >> 3;
    const int t = threadIdx.x, lane = t & 63, w = t >> 6;
    const int bsub = t >> 4;                           // 0..15 (rb-group of 8)
    const int cidx = t & 15;                           // x4 cols
    f32x4 acc = {};
    #pragma unroll 4
    for (int r = 0; r < 8; r++) {
        const int rb = bsub * 8 + r;
        f32x4 v = *(const f32x4*)(partial + ((size_t)rb * 32 + j) * 512 + ct * 64 + cidx * 4);
        acc += v;
    }
    #pragma unroll
    for (int k = 0; k < 4; k++) {
        acc[k] += __shfl_xor(acc[k], 16, 64);
        acc[k] += __shfl_xor(acc[k], 32, 64);
    }
    __shared__ float red[4][64];
    if (lane < 16) {
        #pragma unroll
        for (int k = 0; k < 4; k++) red[w][lane * 4 + k] = acc[k];
    }
    __syncthreads();

    if (t < 64) {
        const int c = ct * 64 + t;
        float S = red[0][t] + red[1][t] + red[2][t] + red[3][t];
        S -= diag[(size_t)c * 32 + j];                 // near-exact cancellation (f32)
        const float invT = 1.0f / *temp;
        const float lp = pos_sim[(c << 5) + j] * invT;
        float term = logf(__expf(lp) + S) - lp;
        term = wsum(term);
        if (t == 0) atomicAdd(loss, term * (1.0f / 16384.0f));
    }
}

extern "C" void kernel_launch(void* const* d_in, const int* in_sizes, int n_in,
                              void* d_out, int out_size, void* d_ws, size_t ws_size,
                              hipStream_t stream)
{
    const float* sent = (const float*)d_in[0];
    const float* aug  = (const float*)d_in[1];
    const float* rel  = (const float*)d_in[2];
    const float* clsw = (const float*)d_in[3];
    const float* clsb = (const float*)d_in[4];
    const int*   lab  = (const int*)d_in[5];
    const float* temp = (const float*)d_in[6];
    float* out = (float*)d_out;

    char* ws = (char*)d_ws;
    __bf16* bagb    = (__bf16*)(ws);                           // 1 MB
    float*  nbsq    = (float*)(ws + (1u << 20));               // 2 KB
    float*  nr      = (float*)(ws + (1u << 20) + 64 * 1024);   // 64 KB
    float*  pos     = (float*)(ws + (1u << 20) + 128 * 1024);  // 64 KB
    __bf16* cwb     = (__bf16*)(ws + (1u << 20) + 192 * 1024); // 128 KB
    float*  scoreg  = (float*)(ws + (1u << 20) + 320 * 1024);  // 64 KB
    float*  diag    = (float*)(ws + (2u << 20) + 64 * 1024);   // 64 KB
    __bf16* repb    = (__bf16*)(ws + (4u << 20));              // 32 MB
    float*  partial = (float*)(ws + (36u << 20));              // 8 MB

    float* loss = out + 27136;

    ka     <<<4096, 256, 0, stream>>>(sent, aug, rel, lab, repb, nr, pos, scoreg,
                                      clsw, cwb, nbsq, loss);
    kb     <<<512, 256, 0, stream>>>(repb, scoreg, bagb, nbsq);
    k4_gemm<<<520, 256, 0, stream>>>(repb, bagb, nr, nbsq, temp, partial, diag,
                                     cwb, clsb, out);
    k5_neg <<<256, 256, 0, stream>>>(partial, diag, pos, temp, loss);
}